// Round 3
// baseline (379.562 us; speedup 1.0000x reference)
//
#include <hip/hip_runtime.h>
#include <hip/hip_bf16.h>
#include <stdint.h>

#define B_ 2
#define S_ 2048
#define D_ 1024
#define H_ 16
#define DK_ 64
#define M_ 4096   // B_*S_
#define K_ 1024

typedef unsigned short u16;
typedef u16   u16x4  __attribute__((ext_vector_type(4)));
typedef short short8 __attribute__((ext_vector_type(8)));
typedef float f32x4  __attribute__((ext_vector_type(4)));

__device__ __forceinline__ u16 f2bf(float f) {
  uint32_t u = __builtin_bit_cast(uint32_t, f);
  u += 0x7FFFu + ((u >> 16) & 1u);   // RNE
  return (u16)(u >> 16);
}

__device__ __forceinline__ void gload_lds16(const void* g, void* l) {
  __builtin_amdgcn_global_load_lds(
      (const __attribute__((address_space(1))) void*)g,
      (__attribute__((address_space(3))) void*)l, 16, 0, 0);
}

// ---------------- fp32 -> bf16 convert (4 elems/thread) ----------------
__global__ __launch_bounds__(256) void cvt_f32_bf16(const float* __restrict__ in,
                                                    u16* __restrict__ out) {
  const int i = (blockIdx.x * 256 + threadIdx.x) * 4;
  const float4 v = *(const float4*)(in + i);
  u16x4 o;
  o[0] = f2bf(v.x); o[1] = f2bf(v.y); o[2] = f2bf(v.z); o[3] = f2bf(v.w);
  *(u16x4*)(out + i) = o;
}

// ---------------- 128x128 bf16 GEMM: C = A @ W^T + bias ----------------
// A: [M_,K_] bf16 row-major.  W: [1024,K_] bf16 row-major (torch Linear weight).
// MODE 0: bf16 out, head-split [B,H,S,DK]   (Q/K; scale folds 1/sqrt(dk) into Q)
// MODE 1: bf16 out, transposed [B,H,DK,S]   (V)
// MODE 2: fp32 out, row-major [M_,1024]     (final projection)
template <int MODE>
__global__ __launch_bounds__(256) void gemm128(const u16* __restrict__ A,
                                               const u16* __restrict__ W,
                                               const float* __restrict__ bias,
                                               void* __restrict__ out,
                                               float scale) {
  __shared__ u16 As[128 * 64];
  __shared__ u16 Bs[128 * 64];
  const int tid = threadIdx.x;
  const int w = tid >> 6, lane = tid & 63;
  const int lr = lane & 15, lk = lane >> 4;
  const int wr = w >> 1, wc = w & 1;
  const int m0 = blockIdx.y * 128, n0 = blockIdx.x * 128;

  f32x4 acc[4][4] = {};

  const int trow  = tid >> 3;         // 0..31
  const int tcolb = (tid & 7) * 16;   // byte offset within a 64-elem (128B) row
  const u16* Abase = A + (size_t)(m0 + trow) * K_;
  const u16* Wbase = W + (size_t)(n0 + trow) * K_;

  for (int k0 = 0; k0 < K_; k0 += 64) {
#pragma unroll
    for (int i = 0; i < 4; ++i) {
      const char* ga = (const char*)(Abase + (size_t)(i * 32) * K_ + k0) + tcolb;
      gload_lds16(ga, (char*)As + i * 4096 + w * 1024);
      const char* gb = (const char*)(Wbase + (size_t)(i * 32) * K_ + k0) + tcolb;
      gload_lds16(gb, (char*)Bs + i * 4096 + w * 1024);
    }
    __syncthreads();
#pragma unroll
    for (int kk = 0; kk < 2; ++kk) {
      short8 af[4], bf[4];
#pragma unroll
      for (int mi = 0; mi < 4; ++mi)
        af[mi] = *(const short8*)&As[(wr * 64 + mi * 16 + lr) * 64 + kk * 32 + lk * 8];
#pragma unroll
      for (int nj = 0; nj < 4; ++nj)
        bf[nj] = *(const short8*)&Bs[(wc * 64 + nj * 16 + lr) * 64 + kk * 32 + lk * 8];
#pragma unroll
      for (int mi = 0; mi < 4; ++mi)
#pragma unroll
        for (int nj = 0; nj < 4; ++nj)
          acc[mi][nj] = __builtin_amdgcn_mfma_f32_16x16x32_bf16(af[mi], bf[nj],
                                                                acc[mi][nj], 0, 0, 0);
    }
    __syncthreads();
  }

#pragma unroll
  for (int nj = 0; nj < 4; ++nj) {
    const int col = n0 + wc * 64 + nj * 16 + lr;
    const float bv = bias[col];
#pragma unroll
    for (int mi = 0; mi < 4; ++mi) {
#pragma unroll
      for (int r = 0; r < 4; ++r) {
        const int row = m0 + wr * 64 + mi * 16 + lk * 4 + r;
        const float val = (acc[mi][nj][r] + bv) * scale;
        if constexpr (MODE == 0) {
          const int b = row >> 11, s = row & 2047;
          const int h = col >> 6, dk = col & 63;
          ((u16*)out)[((size_t)(b * H_ + h) * S_ + s) * DK_ + dk] = f2bf(val);
        } else if constexpr (MODE == 1) {
          const int b = row >> 11, s = row & 2047;
          const int h = col >> 6, dk = col & 63;
          ((u16*)out)[((size_t)(b * H_ + h) * DK_ + dk) * S_ + s] = f2bf(val);
        } else {
          ((float*)out)[(size_t)row * D_ + col] = val;
        }
      }
    }
  }
}

// ---------------- flash attention: per (b,h, 64 q-rows) ----------------
// Qh,Kh: [B,H,S,DK] bf16 (Q pre-scaled by 1/8).  Vt: [B,H,DK,S] bf16.
// O: [B,S,D] bf16.  AW: [B,H,S] fp32 (mean over dk of O).
__global__ __launch_bounds__(256) void flash64(const u16* __restrict__ Qh,
                                               const u16* __restrict__ Kh,
                                               const u16* __restrict__ Vt,
                                               u16* __restrict__ O,
                                               float* __restrict__ AW) {
  __shared__ u16 Ks[64 * 64];
  __shared__ u16 Vs[64 * 64];   // [dk][kv]
  __shared__ u16 Ps[64 * 64];
  const int tid = threadIdx.x;
  const int w = tid >> 6, lane = tid & 63;
  const int lr = lane & 15, lk = lane >> 4;
  const int q0 = blockIdx.x * 64;
  const int bh = blockIdx.y;          // b*H + h
  const int b = bh >> 4, h = bh & 15;

  const u16* Qg = Qh + ((size_t)bh * S_ + q0 + w * 16 + lr) * DK_;
  short8 qf[2];
  qf[0] = *(const short8*)(Qg + lk * 8);
  qf[1] = *(const short8*)(Qg + 32 + lk * 8);

  float mrow[4], lrow[4];
  f32x4 o[4] = {};
#pragma unroll
  for (int r = 0; r < 4; ++r) { mrow[r] = -__builtin_inff(); lrow[r] = 0.f; }

  const int trow  = tid >> 3;
  const int tcolb = (tid & 7) * 16;
  const u16* Kgb = Kh + (size_t)bh * S_ * DK_;
  const u16* Vgb = Vt + (size_t)bh * DK_ * S_;

  for (int kv0 = 0; kv0 <= q0; kv0 += 64) {
#pragma unroll
    for (int i = 0; i < 2; ++i) {
      const char* gk = (const char*)(Kgb + (size_t)(kv0 + i * 32 + trow) * DK_) + tcolb;
      gload_lds16(gk, (char*)Ks + i * 4096 + w * 1024);
      const char* gv = (const char*)(Vgb + (size_t)(i * 32 + trow) * S_ + kv0) + tcolb;
      gload_lds16(gv, (char*)Vs + i * 4096 + w * 1024);
    }
    __syncthreads();

    // S = Q K^T (Q already has 1/sqrt(dk))
    f32x4 sa[4] = {};
#pragma unroll
    for (int kk = 0; kk < 2; ++kk)
#pragma unroll
      for (int nj = 0; nj < 4; ++nj) {
        const short8 kf = *(const short8*)&Ks[(nj * 16 + lr) * 64 + kk * 32 + lk * 8];
        sa[nj] = __builtin_amdgcn_mfma_f32_16x16x32_bf16(qf[kk], kf, sa[nj], 0, 0, 0);
      }

    if (kv0 == q0) {  // diagonal tile: causal mask (col > row -> -inf)
#pragma unroll
      for (int nj = 0; nj < 4; ++nj)
#pragma unroll
        for (int r = 0; r < 4; ++r)
          if (nj * 16 + lr > w * 16 + lk * 4 + r) sa[nj][r] = -1e30f;
    }

    // online softmax update (rows owned: lk*4 + r; 16 lanes share a row)
#pragma unroll
    for (int r = 0; r < 4; ++r) {
      float mx = fmaxf(fmaxf(sa[0][r], sa[1][r]), fmaxf(sa[2][r], sa[3][r]));
#pragma unroll
      for (int d = 1; d < 16; d <<= 1) mx = fmaxf(mx, __shfl_xor(mx, d));
      const float mn = fmaxf(mrow[r], mx);
      const float sc = __expf(mrow[r] - mn);
      mrow[r] = mn;
      float rs = 0.f;
#pragma unroll
      for (int nj = 0; nj < 4; ++nj) {
        const float p = __expf(sa[nj][r] - mn);
        sa[nj][r] = p;
        rs += p;
      }
#pragma unroll
      for (int d = 1; d < 16; d <<= 1) rs += __shfl_xor(rs, d);
      lrow[r] = lrow[r] * sc + rs;
#pragma unroll
      for (int nj = 0; nj < 4; ++nj) o[nj][r] *= sc;
    }

    // P -> LDS (bf16), per-wave private 16-row slab
#pragma unroll
    for (int nj = 0; nj < 4; ++nj)
#pragma unroll
      for (int r = 0; r < 4; ++r)
        Ps[(w * 16 + lk * 4 + r) * 64 + nj * 16 + lr] = f2bf(sa[nj][r]);

    // O += P @ V   (A = P rows, B[k=kv][n=dk] = Vs[dk][kv])
#pragma unroll
    for (int kk = 0; kk < 2; ++kk) {
      const short8 pa = *(const short8*)&Ps[(w * 16 + lr) * 64 + kk * 32 + lk * 8];
#pragma unroll
      for (int nj = 0; nj < 4; ++nj) {
        const short8 vf = *(const short8*)&Vs[(nj * 16 + lr) * 64 + kk * 32 + lk * 8];
        o[nj] = __builtin_amdgcn_mfma_f32_16x16x32_bf16(pa, vf, o[nj], 0, 0, 0);
      }
    }
    __syncthreads();
  }

#pragma unroll
  for (int r = 0; r < 4; ++r) {
    const int rowq = q0 + w * 16 + lk * 4 + r;
    const float inv = 1.f / lrow[r];
    float rsum = 0.f;
#pragma unroll
    for (int nj = 0; nj < 4; ++nj) {
      const float v = o[nj][r] * inv;
      O[((size_t)(b * S_ + rowq)) * D_ + h * 64 + nj * 16 + lr] = f2bf(v);
      rsum += v;
    }
#pragma unroll
    for (int d = 1; d < 16; d <<= 1) rsum += __shfl_xor(rsum, d);
    if (lr == 0) AW[(size_t)bh * S_ + rowq] = rsum * (1.f / 64.f);
  }
}

extern "C" void kernel_launch(void* const* d_in, const int* in_sizes, int n_in,
                              void* d_out, int out_size, void* d_ws, size_t ws_size,
                              hipStream_t stream) {
  const float* q  = (const float*)d_in[0];
  const float* k  = (const float*)d_in[1];
  const float* v  = (const float*)d_in[2];
  const float* Wq = (const float*)d_in[4];
  const float* bq = (const float*)d_in[5];
  const float* Wk = (const float*)d_in[6];
  const float* bk = (const float*)d_in[7];
  const float* Wv = (const float*)d_in[8];
  const float* bv = (const float*)d_in[9];
  const float* Wo = (const float*)d_in[10];
  const float* bo = (const float*)d_in[11];
  float* out = (float*)d_out;
  float* aw  = out + (size_t)M_ * D_;   // attn_weights tail [B,H,S]

  char* ws = (char*)d_ws;
  u16* Qh  = (u16*)(ws);
  u16* Kh  = (u16*)(ws + (8u << 20));
  u16* Vtb = (u16*)(ws + (16u << 20));
  u16* Ob  = (u16*)(ws + (24u << 20));
  u16* Xb  = (u16*)(ws + (32u << 20));
  u16* Wqb = (u16*)(ws + (40u << 20));
  u16* Wkb = (u16*)(ws + (42u << 20));
  u16* Wvb = (u16*)(ws + (44u << 20));
  u16* Wob = (u16*)(ws + (46u << 20));

  cvt_f32_bf16<<<1024, 256, 0, stream>>>(Wq, Wqb);
  cvt_f32_bf16<<<1024, 256, 0, stream>>>(Wk, Wkb);
  cvt_f32_bf16<<<1024, 256, 0, stream>>>(Wv, Wvb);
  cvt_f32_bf16<<<1024, 256, 0, stream>>>(Wo, Wob);

  const dim3 gg(8, 32);  // N/128, M/128
  cvt_f32_bf16<<<4096, 256, 0, stream>>>(q, Xb);
  gemm128<0><<<gg, 256, 0, stream>>>(Xb, Wqb, bq, Qh, 0.125f);  // fold 1/sqrt(64)
  cvt_f32_bf16<<<4096, 256, 0, stream>>>(k, Xb);
  gemm128<0><<<gg, 256, 0, stream>>>(Xb, Wkb, bk, Kh, 1.0f);
  cvt_f32_bf16<<<4096, 256, 0, stream>>>(v, Xb);
  gemm128<1><<<gg, 256, 0, stream>>>(Xb, Wvb, bv, Vtb, 1.0f);

  flash64<<<dim3(S_ / 64, B_ * H_), 256, 0, stream>>>(Qh, Kh, Vtb, Ob, aw);

  gemm128<2><<<gg, 256, 0, stream>>>(Ob, Wob, bo, out, 1.0f);
}

// Round 5
// 365.819 us; speedup vs baseline: 1.0376x; 1.0376x over previous
//
#include <hip/hip_runtime.h>
#include <hip/hip_bf16.h>
#include <stdint.h>

#define B_ 2
#define S_ 2048
#define D_ 1024
#define H_ 16
#define DK_ 64
#define M_ 4096   // B_*S_
#define K_ 1024

typedef unsigned short u16;
typedef u16   u16x4  __attribute__((ext_vector_type(4)));
typedef short short8 __attribute__((ext_vector_type(8)));
typedef float f32x4  __attribute__((ext_vector_type(4)));

__device__ __forceinline__ u16 f2bf(float f) {
  uint32_t u = __builtin_bit_cast(uint32_t, f);
  u += 0x7FFFu + ((u >> 16) & 1u);   // RNE
  return (u16)(u >> 16);
}

__device__ __forceinline__ void gload_lds16(const void* g, void* l) {
  __builtin_amdgcn_global_load_lds(
      (const __attribute__((address_space(1))) void*)g,
      (__attribute__((address_space(3))) void*)l, 16, 0, 0);
}

// ---------------- fp32 -> bf16 weight converts, 4 tensors in one launch ----
__global__ __launch_bounds__(256) void cvt4w(const float* __restrict__ a,
                                             const float* __restrict__ b,
                                             const float* __restrict__ c,
                                             const float* __restrict__ d,
                                             u16* __restrict__ oa, u16* __restrict__ ob,
                                             u16* __restrict__ oc, u16* __restrict__ od) {
  const int z = blockIdx.y;
  const float* in = z == 0 ? a : (z == 1 ? b : (z == 2 ? c : d));
  u16* out = z == 0 ? oa : (z == 1 ? ob : (z == 2 ? oc : od));
  const int i = (blockIdx.x * 256 + threadIdx.x) * 4;
  const float4 v = *(const float4*)(in + i);
  u16x4 o;
  o[0] = f2bf(v.x); o[1] = f2bf(v.y); o[2] = f2bf(v.z); o[3] = f2bf(v.w);
  *(u16x4*)(out + i) = o;
}

// ---------------- fused QKV GEMM: 3 blocks/CU, fp32 A staged raw ----------
// z=0: Q -> [B,H,S,DK] *0.125   z=1: K -> [B,H,S,DK]   z=2: V -> [B,H,DK,S]
__global__ __launch_bounds__(256) void gemm_qkv(
    const float* __restrict__ Aq, const float* __restrict__ Ak, const float* __restrict__ Av,
    const u16* __restrict__ Wqp, const u16* __restrict__ Wkp, const u16* __restrict__ Wvp,
    const float* __restrict__ bqp, const float* __restrict__ bkp, const float* __restrict__ bvp,
    u16* __restrict__ oq, u16* __restrict__ okk, u16* __restrict__ ov) {
  __shared__ float As[128 * 64];   // 32 KB fp32 activations
  __shared__ u16  Bs[128 * 64];    // 16 KB bf16 weights
  const int z = blockIdx.z;
  const float* A    = z == 0 ? Aq  : (z == 1 ? Ak  : Av);
  const u16*   W    = z == 0 ? Wqp : (z == 1 ? Wkp : Wvp);
  const float* bias = z == 0 ? bqp : (z == 1 ? bkp : bvp);
  u16* out          = z == 0 ? oq  : (z == 1 ? okk : ov);
  const float scale = z == 0 ? 0.125f : 1.0f;

  const int tid = threadIdx.x;
  const int w = tid >> 6, lane = tid & 63;
  const int lr = lane & 15, lk = lane >> 4;
  const int wr = w >> 1, wc = w & 1;
  const int m0 = blockIdx.y * 128, n0 = blockIdx.x * 128;

  f32x4 acc[4][4] = {};

  const int arow  = w * 4 + (lane >> 4);   // A stage: 4 fp32 rows/wave per iter
  const int acolb = (lane & 15) * 16;
  const int trow  = tid >> 3;              // W stage: 8 bf16 rows/wave per iter
  const int tcolb = (tid & 7) * 16;
  const u16* Wbase = W + (size_t)(n0 + trow) * K_;

  for (int k0 = 0; k0 < K_; k0 += 64) {
#pragma unroll
    for (int i = 0; i < 8; ++i) {
      const char* ga = (const char*)(A + (size_t)(m0 + i * 16 + arow) * K_ + k0) + acolb;
      gload_lds16(ga, (char*)As + i * 4096 + w * 1024);
    }
#pragma unroll
    for (int i = 0; i < 4; ++i) {
      const char* gb = (const char*)(Wbase + (size_t)(i * 32) * K_ + k0) + tcolb;
      gload_lds16(gb, (char*)Bs + i * 4096 + w * 1024);
    }
    __syncthreads();
#pragma unroll
    for (int kk = 0; kk < 2; ++kk) {
      short8 af[4], bf[4];
#pragma unroll
      for (int mi = 0; mi < 4; ++mi) {
        const char* ap = (const char*)As + (wr * 64 + mi * 16 + lr) * 256 + kk * 128 + lk * 32;
        const f32x4 lo = *(const f32x4*)ap;
        const f32x4 hi = *(const f32x4*)(ap + 16);
#pragma unroll
        for (int e = 0; e < 4; ++e) {
          af[mi][e]     = (short)f2bf(lo[e]);
          af[mi][4 + e] = (short)f2bf(hi[e]);
        }
      }
#pragma unroll
      for (int nj = 0; nj < 4; ++nj)
        bf[nj] = *(const short8*)&Bs[(wc * 64 + nj * 16 + lr) * 64 + kk * 32 + lk * 8];
#pragma unroll
      for (int mi = 0; mi < 4; ++mi)
#pragma unroll
        for (int nj = 0; nj < 4; ++nj)
          acc[mi][nj] = __builtin_amdgcn_mfma_f32_16x16x32_bf16(af[mi], bf[nj],
                                                                acc[mi][nj], 0, 0, 0);
    }
    __syncthreads();
  }

#pragma unroll
  for (int nj = 0; nj < 4; ++nj) {
    const int col = n0 + wc * 64 + nj * 16 + lr;
    const float bv = bias[col];
    const int h = col >> 6, dk = col & 63;
#pragma unroll
    for (int mi = 0; mi < 4; ++mi) {
#pragma unroll
      for (int r = 0; r < 4; ++r) {
        const int row = m0 + wr * 64 + mi * 16 + lk * 4 + r;
        const float val = (acc[mi][nj][r] + bv) * scale;
        const int b = row >> 11, s = row & 2047;
        if (z != 2)
          out[((size_t)(b * H_ + h) * S_ + s) * DK_ + dk] = f2bf(val);
        else
          out[((size_t)(b * H_ + h) * DK_ + dk) * S_ + s] = f2bf(val);
      }
    }
  }
}

// ---------------- out-projection GEMM (bf16 A, fp32 out) -------------------
__global__ __launch_bounds__(256) void gemm_out(const u16* __restrict__ A,
                                                const u16* __restrict__ W,
                                                const float* __restrict__ bias,
                                                float* __restrict__ out) {
  __shared__ u16 As[128 * 64];
  __shared__ u16 Bs[128 * 64];
  const int tid = threadIdx.x;
  const int w = tid >> 6, lane = tid & 63;
  const int lr = lane & 15, lk = lane >> 4;
  const int wr = w >> 1, wc = w & 1;
  const int m0 = blockIdx.y * 128, n0 = blockIdx.x * 128;

  f32x4 acc[4][4] = {};

  const int trow  = tid >> 3;
  const int tcolb = (tid & 7) * 16;
  const u16* Abase = A + (size_t)(m0 + trow) * K_;
  const u16* Wbase = W + (size_t)(n0 + trow) * K_;

  for (int k0 = 0; k0 < K_; k0 += 64) {
#pragma unroll
    for (int i = 0; i < 4; ++i) {
      const char* ga = (const char*)(Abase + (size_t)(i * 32) * K_ + k0) + tcolb;
      gload_lds16(ga, (char*)As + i * 4096 + w * 1024);
      const char* gb = (const char*)(Wbase + (size_t)(i * 32) * K_ + k0) + tcolb;
      gload_lds16(gb, (char*)Bs + i * 4096 + w * 1024);
    }
    __syncthreads();
#pragma unroll
    for (int kk = 0; kk < 2; ++kk) {
      short8 af[4], bf[4];
#pragma unroll
      for (int mi = 0; mi < 4; ++mi)
        af[mi] = *(const short8*)&As[(wr * 64 + mi * 16 + lr) * 64 + kk * 32 + lk * 8];
#pragma unroll
      for (int nj = 0; nj < 4; ++nj)
        bf[nj] = *(const short8*)&Bs[(wc * 64 + nj * 16 + lr) * 64 + kk * 32 + lk * 8];
#pragma unroll
      for (int mi = 0; mi < 4; ++mi)
#pragma unroll
        for (int nj = 0; nj < 4; ++nj)
          acc[mi][nj] = __builtin_amdgcn_mfma_f32_16x16x32_bf16(af[mi], bf[nj],
                                                                acc[mi][nj], 0, 0, 0);
    }
    __syncthreads();
  }

#pragma unroll
  for (int nj = 0; nj < 4; ++nj) {
    const int col = n0 + wc * 64 + nj * 16 + lr;
    const float bv = bias[col];
#pragma unroll
    for (int mi = 0; mi < 4; ++mi)
#pragma unroll
      for (int r = 0; r < 4; ++r) {
        const int row = m0 + wr * 64 + mi * 16 + lk * 4 + r;
        out[(size_t)row * D_ + col] = acc[mi][nj][r] + bv;
      }
  }
}

// ---------------- flash attention, XOR-swizzled LDS ------------------------
// Qh,Kh: [B,H,S,DK] bf16 (Q pre-scaled by 1/8).  Vt: [B,H,DK,S] bf16.
// LDS layout: linear dest via global_load_lds; SOURCE column pre-swizzled by
// byte ^= ((row&7)<<4); all reads apply the same XOR (involution, rule #21).
__global__ __launch_bounds__(256) void flash64(const u16* __restrict__ Qh,
                                               const u16* __restrict__ Kh,
                                               const u16* __restrict__ Vt,
                                               u16* __restrict__ O,
                                               float* __restrict__ AW) {
  __shared__ u16 Ks[64 * 64];
  __shared__ u16 Vs[64 * 64];   // [dk][kv]
  __shared__ u16 Ps[64 * 64];
  const int tid = threadIdx.x;
  const int w = tid >> 6, lane = tid & 63;
  const int lr = lane & 15, lk = lane >> 4;
  const int q0 = blockIdx.x * 64;
  const int bh = blockIdx.y;          // b*H + h
  const int b = bh >> 4, h = bh & 15;

  const u16* Qg = Qh + ((size_t)bh * S_ + q0 + w * 16 + lr) * DK_;
  short8 qf[2];
  qf[0] = *(const short8*)(Qg + lk * 8);
  qf[1] = *(const short8*)(Qg + 32 + lk * 8);

  float mrow[4], lrow[4];
  f32x4 o[4] = {};
#pragma unroll
  for (int r = 0; r < 4; ++r) { mrow[r] = -__builtin_inff(); lrow[r] = 0.f; }

  const int trow  = tid >> 3;
  const int tswz  = ((tid & 7) * 16) ^ ((trow & 7) << 4);   // pre-swizzled source col
  const int rswz  = (lr & 7) << 4;                          // read-side XOR
  const u16* Kgb = Kh + (size_t)bh * S_ * DK_;
  const u16* Vgb = Vt + (size_t)bh * DK_ * S_;

  for (int kv0 = 0; kv0 <= q0; kv0 += 64) {
#pragma unroll
    for (int i = 0; i < 2; ++i) {
      const char* gk = (const char*)(Kgb + (size_t)(kv0 + i * 32 + trow) * DK_) + tswz;
      gload_lds16(gk, (char*)Ks + i * 4096 + w * 1024);
      const char* gv = (const char*)(Vgb + (size_t)(i * 32 + trow) * S_ + kv0) + tswz;
      gload_lds16(gv, (char*)Vs + i * 4096 + w * 1024);
    }
    __syncthreads();

    // S = Q K^T (Q already has 1/sqrt(dk))
    f32x4 sa[4] = {};
#pragma unroll
    for (int kk = 0; kk < 2; ++kk)
#pragma unroll
      for (int nj = 0; nj < 4; ++nj) {
        const short8 kf = *(const short8*)((const char*)Ks + (nj * 16 + lr) * 128 +
                                           ((kk * 64 + lk * 16) ^ rswz));
        sa[nj] = __builtin_amdgcn_mfma_f32_16x16x32_bf16(qf[kk], kf, sa[nj], 0, 0, 0);
      }

    if (kv0 == q0) {  // diagonal tile: causal mask (col > row -> -inf)
#pragma unroll
      for (int nj = 0; nj < 4; ++nj)
#pragma unroll
        for (int r = 0; r < 4; ++r)
          if (nj * 16 + lr > w * 16 + lk * 4 + r) sa[nj][r] = -1e30f;
    }

    // online softmax update (rows owned: lk*4 + r; 16 lanes share a row)
#pragma unroll
    for (int r = 0; r < 4; ++r) {
      float mx = fmaxf(fmaxf(sa[0][r], sa[1][r]), fmaxf(sa[2][r], sa[3][r]));
#pragma unroll
      for (int d = 1; d < 16; d <<= 1) mx = fmaxf(mx, __shfl_xor(mx, d));
      const float mn = fmaxf(mrow[r], mx);
      const float sc = __expf(mrow[r] - mn);
      mrow[r] = mn;
      float rs = 0.f;
#pragma unroll
      for (int nj = 0; nj < 4; ++nj) {
        const float p = __expf(sa[nj][r] - mn);
        sa[nj][r] = p;
        rs += p;
      }
#pragma unroll
      for (int d = 1; d < 16; d <<= 1) rs += __shfl_xor(rs, d);
      lrow[r] = lrow[r] * sc + rs;
#pragma unroll
      for (int nj = 0; nj < 4; ++nj) o[nj][r] *= sc;
    }

    // P -> LDS (bf16, swizzled)
#pragma unroll
    for (int nj = 0; nj < 4; ++nj)
#pragma unroll
      for (int r = 0; r < 4; ++r) {
        const int rp = w * 16 + lk * 4 + r;
        *(u16*)((char*)Ps + rp * 128 + (((nj * 16 + lr) * 2) ^ ((rp & 7) << 4))) =
            f2bf(sa[nj][r]);
      }

    // O += P @ V   (A = P rows, B[k=kv][n=dk] = Vs[dk][kv])
#pragma unroll
    for (int kk = 0; kk < 2; ++kk) {
      const short8 pa = *(const short8*)((const char*)Ps + (w * 16 + lr) * 128 +
                                         ((kk * 64 + lk * 16) ^ rswz));
#pragma unroll
      for (int nj = 0; nj < 4; ++nj) {
        const short8 vf = *(const short8*)((const char*)Vs + (nj * 16 + lr) * 128 +
                                           ((kk * 64 + lk * 16) ^ rswz));
        o[nj] = __builtin_amdgcn_mfma_f32_16x16x32_bf16(pa, vf, o[nj], 0, 0, 0);
      }
    }
    __syncthreads();
  }

#pragma unroll
  for (int r = 0; r < 4; ++r) {
    const int rowq = q0 + w * 16 + lk * 4 + r;
    const float inv = 1.f / lrow[r];
    float rsum = 0.f;
#pragma unroll
    for (int nj = 0; nj < 4; ++nj) {
      const float v = o[nj][r] * inv;
      O[((size_t)(b * S_ + rowq)) * D_ + h * 64 + nj * 16 + lr] = f2bf(v);
      rsum += v;
    }
#pragma unroll
    for (int d = 1; d < 16; d <<= 1) rsum += __shfl_xor(rsum, d);
    if (lr == 0) AW[(size_t)bh * S_ + rowq] = rsum * (1.f / 64.f);
  }
}

extern "C" void kernel_launch(void* const* d_in, const int* in_sizes, int n_in,
                              void* d_out, int out_size, void* d_ws, size_t ws_size,
                              hipStream_t stream) {
  const float* q  = (const float*)d_in[0];
  const float* k  = (const float*)d_in[1];
  const float* v  = (const float*)d_in[2];
  const float* Wq = (const float*)d_in[4];
  const float* bq = (const float*)d_in[5];
  const float* Wk = (const float*)d_in[6];
  const float* bk = (const float*)d_in[7];
  const float* Wv = (const float*)d_in[8];
  const float* bv = (const float*)d_in[9];
  const float* Wo = (const float*)d_in[10];
  const float* bo = (const float*)d_in[11];
  float* out = (float*)d_out;
  float* aw  = out + (size_t)M_ * D_;   // attn_weights tail [B,H,S]

  char* ws = (char*)d_ws;               // 40 MB total (proven ws >= 48 MB)
  u16* Qh  = (u16*)(ws);                //  0- 8 MB
  u16* Kh  = (u16*)(ws + (8u << 20));   //  8-16
  u16* Vtb = (u16*)(ws + (16u << 20));  // 16-24
  u16* Ob  = (u16*)(ws + (24u << 20));  // 24-32
  u16* Wqb = (u16*)(ws + (32u << 20));  // 32-34
  u16* Wkb = (u16*)(ws + (34u << 20));
  u16* Wvb = (u16*)(ws + (36u << 20));
  u16* Wob = (u16*)(ws + (38u << 20));

  cvt4w<<<dim3(1024, 4), 256, 0, stream>>>(Wq, Wk, Wv, Wo, Wqb, Wkb, Wvb, Wob);

  gemm_qkv<<<dim3(8, 32, 3), 256, 0, stream>>>(q, k, v, Wqb, Wkb, Wvb,
                                               bq, bk, bv, Qh, Kh, Vtb);

  flash64<<<dim3(S_ / 64, B_ * H_), 256, 0, stream>>>(Qh, Kh, Vtb, Ob, aw);

  gemm_out<<<dim3(8, 32), 256, 0, stream>>>(Ob, Wob, bo, out);
}

// Round 6
// 301.928 us; speedup vs baseline: 1.2571x; 1.2116x over previous
//
#include <hip/hip_runtime.h>
#include <hip/hip_bf16.h>
#include <stdint.h>

#define B_ 2
#define S_ 2048
#define D_ 1024
#define H_ 16
#define DK_ 64
#define M_ 4096   // B_*S_
#define K_ 1024

typedef unsigned short u16;
typedef u16   u16x4  __attribute__((ext_vector_type(4)));
typedef short short8 __attribute__((ext_vector_type(8)));
typedef float f32x4  __attribute__((ext_vector_type(4)));

__device__ __forceinline__ u16 f2bf(float f) {
  uint32_t u = __builtin_bit_cast(uint32_t, f);
  u += 0x7FFFu + ((u >> 16) & 1u);   // RNE
  return (u16)(u >> 16);
}

__device__ __forceinline__ void gload_lds16(const void* g, void* l) {
  __builtin_amdgcn_global_load_lds(
      (const __attribute__((address_space(1))) void*)g,
      (__attribute__((address_space(3))) void*)l, 16, 0, 0);
}

// ---------------- fp32 -> bf16 weight converts, 4 tensors in one launch ----
__global__ __launch_bounds__(256) void cvt4w(const float* __restrict__ a,
                                             const float* __restrict__ b,
                                             const float* __restrict__ c,
                                             const float* __restrict__ d,
                                             u16* __restrict__ oa, u16* __restrict__ ob,
                                             u16* __restrict__ oc, u16* __restrict__ od) {
  const int z = blockIdx.y;
  const float* in = z == 0 ? a : (z == 1 ? b : (z == 2 ? c : d));
  u16* out = z == 0 ? oa : (z == 1 ? ob : (z == 2 ? oc : od));
  const int i = (blockIdx.x * 256 + threadIdx.x) * 4;
  const float4 v = *(const float4*)(in + i);
  u16x4 o;
  o[0] = f2bf(v.x); o[1] = f2bf(v.y); o[2] = f2bf(v.z); o[3] = f2bf(v.w);
  *(u16x4*)(out + i) = o;
}

// ---------------- fused QKV GEMM: 3 blocks/CU, fp32 A staged raw ----------
// z=0: Q -> [B,H,S,DK] *0.125   z=1: K -> [B,H,S,DK]   z=2: V -> [B,H,DK,S]
__global__ __launch_bounds__(256) void gemm_qkv(
    const float* __restrict__ Aq, const float* __restrict__ Ak, const float* __restrict__ Av,
    const u16* __restrict__ Wqp, const u16* __restrict__ Wkp, const u16* __restrict__ Wvp,
    const float* __restrict__ bqp, const float* __restrict__ bkp, const float* __restrict__ bvp,
    u16* __restrict__ oq, u16* __restrict__ okk, u16* __restrict__ ov) {
  __shared__ float As[128 * 64];   // 32 KB fp32 activations
  __shared__ u16  Bs[128 * 64];    // 16 KB bf16 weights
  const int z = blockIdx.z;
  const float* A    = z == 0 ? Aq  : (z == 1 ? Ak  : Av);
  const u16*   W    = z == 0 ? Wqp : (z == 1 ? Wkp : Wvp);
  const float* bias = z == 0 ? bqp : (z == 1 ? bkp : bvp);
  u16* out          = z == 0 ? oq  : (z == 1 ? okk : ov);
  const float scale = z == 0 ? 0.125f : 1.0f;

  const int tid = threadIdx.x;
  const int w = tid >> 6, lane = tid & 63;
  const int lr = lane & 15, lk = lane >> 4;
  const int wr = w >> 1, wc = w & 1;
  const int m0 = blockIdx.y * 128, n0 = blockIdx.x * 128;

  f32x4 acc[4][4] = {};

  const int arow  = w * 4 + (lane >> 4);   // A stage: 4 fp32 rows/wave per iter
  const int acolb = (lane & 15) * 16;
  const int trow  = tid >> 3;              // W stage: 8 bf16 rows/wave per iter
  const int tcolb = (tid & 7) * 16;
  const u16* Wbase = W + (size_t)(n0 + trow) * K_;

  for (int k0 = 0; k0 < K_; k0 += 64) {
#pragma unroll
    for (int i = 0; i < 8; ++i) {
      const char* ga = (const char*)(A + (size_t)(m0 + i * 16 + arow) * K_ + k0) + acolb;
      gload_lds16(ga, (char*)As + i * 4096 + w * 1024);
    }
#pragma unroll
    for (int i = 0; i < 4; ++i) {
      const char* gb = (const char*)(Wbase + (size_t)(i * 32) * K_ + k0) + tcolb;
      gload_lds16(gb, (char*)Bs + i * 4096 + w * 1024);
    }
    __syncthreads();
#pragma unroll
    for (int kk = 0; kk < 2; ++kk) {
      short8 af[4], bf[4];
#pragma unroll
      for (int mi = 0; mi < 4; ++mi) {
        const char* ap = (const char*)As + (wr * 64 + mi * 16 + lr) * 256 + kk * 128 + lk * 32;
        const f32x4 lo = *(const f32x4*)ap;
        const f32x4 hi = *(const f32x4*)(ap + 16);
#pragma unroll
        for (int e = 0; e < 4; ++e) {
          af[mi][e]     = (short)f2bf(lo[e]);
          af[mi][4 + e] = (short)f2bf(hi[e]);
        }
      }
#pragma unroll
      for (int nj = 0; nj < 4; ++nj)
        bf[nj] = *(const short8*)&Bs[(wc * 64 + nj * 16 + lr) * 64 + kk * 32 + lk * 8];
#pragma unroll
      for (int mi = 0; mi < 4; ++mi)
#pragma unroll
        for (int nj = 0; nj < 4; ++nj)
          acc[mi][nj] = __builtin_amdgcn_mfma_f32_16x16x32_bf16(af[mi], bf[nj],
                                                                acc[mi][nj], 0, 0, 0);
    }
    __syncthreads();
  }

#pragma unroll
  for (int nj = 0; nj < 4; ++nj) {
    const int col = n0 + wc * 64 + nj * 16 + lr;
    const float bv = bias[col];
    const int h = col >> 6, dk = col & 63;
#pragma unroll
    for (int mi = 0; mi < 4; ++mi) {
#pragma unroll
      for (int r = 0; r < 4; ++r) {
        const int row = m0 + wr * 64 + mi * 16 + lk * 4 + r;
        const float val = (acc[mi][nj][r] + bv) * scale;
        const int b = row >> 11, s = row & 2047;
        if (z != 2)
          out[((size_t)(b * H_ + h) * S_ + s) * DK_ + dk] = f2bf(val);
        else
          out[((size_t)(b * H_ + h) * DK_ + dk) * S_ + s] = f2bf(val);
      }
    }
  }
}

// ---------------- out-projection GEMM (bf16 A, fp32 out) -------------------
__global__ __launch_bounds__(256) void gemm_out(const u16* __restrict__ A,
                                                const u16* __restrict__ W,
                                                const float* __restrict__ bias,
                                                float* __restrict__ out) {
  __shared__ u16 As[128 * 64];
  __shared__ u16 Bs[128 * 64];
  const int tid = threadIdx.x;
  const int w = tid >> 6, lane = tid & 63;
  const int lr = lane & 15, lk = lane >> 4;
  const int wr = w >> 1, wc = w & 1;
  const int m0 = blockIdx.y * 128, n0 = blockIdx.x * 128;

  f32x4 acc[4][4] = {};

  const int trow  = tid >> 3;
  const int tcolb = (tid & 7) * 16;
  const u16* Abase = A + (size_t)(m0 + trow) * K_;
  const u16* Wbase = W + (size_t)(n0 + trow) * K_;

  for (int k0 = 0; k0 < K_; k0 += 64) {
#pragma unroll
    for (int i = 0; i < 4; ++i) {
      const char* ga = (const char*)(Abase + (size_t)(i * 32) * K_ + k0) + tcolb;
      gload_lds16(ga, (char*)As + i * 4096 + w * 1024);
      const char* gb = (const char*)(Wbase + (size_t)(i * 32) * K_ + k0) + tcolb;
      gload_lds16(gb, (char*)Bs + i * 4096 + w * 1024);
    }
    __syncthreads();
#pragma unroll
    for (int kk = 0; kk < 2; ++kk) {
      short8 af[4], bf[4];
#pragma unroll
      for (int mi = 0; mi < 4; ++mi)
        af[mi] = *(const short8*)&As[(wr * 64 + mi * 16 + lr) * 64 + kk * 32 + lk * 8];
#pragma unroll
      for (int nj = 0; nj < 4; ++nj)
        bf[nj] = *(const short8*)&Bs[(wc * 64 + nj * 16 + lr) * 64 + kk * 32 + lk * 8];
#pragma unroll
      for (int mi = 0; mi < 4; ++mi)
#pragma unroll
        for (int nj = 0; nj < 4; ++nj)
          acc[mi][nj] = __builtin_amdgcn_mfma_f32_16x16x32_bf16(af[mi], bf[nj],
                                                                acc[mi][nj], 0, 0, 0);
    }
    __syncthreads();
  }

#pragma unroll
  for (int nj = 0; nj < 4; ++nj) {
    const int col = n0 + wc * 64 + nj * 16 + lr;
    const float bv = bias[col];
#pragma unroll
    for (int mi = 0; mi < 4; ++mi)
#pragma unroll
      for (int r = 0; r < 4; ++r) {
        const int row = m0 + wr * 64 + mi * 16 + lk * 4 + r;
        out[(size_t)row * D_ + col] = acc[mi][nj][r] + bv;
      }
  }
}

// ---------------- flash attention v2: double-buffered, XCD-local -----------
// grid = (B*H, S/64).  bh = blockIdx.x  => same-bh blocks land on same XCD
// (dispatch p = y*32+x, p%8 = bh%8).  qt reversed => longest blocks first.
// K/V double-buffered: STAGE(t+1) issued BEFORE compute(t); single
// __syncthreads per iter AFTER compute => stage latency hidden under compute.
__global__ __launch_bounds__(256) void flash64(const u16* __restrict__ Qh,
                                               const u16* __restrict__ Kh,
                                               const u16* __restrict__ Vt,
                                               u16* __restrict__ O,
                                               float* __restrict__ AW) {
  __shared__ u16 Ks[2][64 * 64];
  __shared__ u16 Vs[2][64 * 64];   // [dk][kv]
  __shared__ u16 Ps[64 * 64];
  const int tid = threadIdx.x;
  const int w = tid >> 6, lane = tid & 63;
  const int lr = lane & 15, lk = lane >> 4;
  const int bh = blockIdx.x;                    // b*H + h
  const int qt = (gridDim.y - 1) - blockIdx.y;  // longest-first
  const int q0 = qt * 64;
  const int b = bh >> 4, h = bh & 15;
  const int nt = qt + 1;

  const u16* Qg = Qh + ((size_t)bh * S_ + q0 + w * 16 + lr) * DK_;
  short8 qf[2];
  qf[0] = *(const short8*)(Qg + lk * 8);
  qf[1] = *(const short8*)(Qg + 32 + lk * 8);

  float mrow[4], lrow[4];
  f32x4 o[4] = {};
#pragma unroll
  for (int r = 0; r < 4; ++r) { mrow[r] = -__builtin_inff(); lrow[r] = 0.f; }

  const int trow = tid >> 3;
  const int tswz = ((tid & 7) * 16) ^ ((trow & 7) << 4);   // pre-swizzled source col
  const int rswz = (lr & 7) << 4;                          // read-side XOR
  const u16* Kgb = Kh + (size_t)bh * S_ * DK_;
  const u16* Vgb = Vt + (size_t)bh * DK_ * S_;

  auto STAGE = [&](int t, int d) {
    const int kv0 = t * 64;
#pragma unroll
    for (int i = 0; i < 2; ++i) {
      const char* gk = (const char*)(Kgb + (size_t)(kv0 + i * 32 + trow) * DK_) + tswz;
      gload_lds16(gk, (char*)Ks[d] + i * 4096 + w * 1024);
      const char* gv = (const char*)(Vgb + (size_t)(i * 32 + trow) * S_ + kv0) + tswz;
      gload_lds16(gv, (char*)Vs[d] + i * 4096 + w * 1024);
    }
  };

  STAGE(0, 0);
  __syncthreads();

  int cur = 0;
  for (int t = 0; t < nt; ++t) {
    if (t + 1 < nt) STAGE(t + 1, cur ^ 1);   // issue next-tile loads early

    // S = Q K^T (Q already has 1/sqrt(dk))
    f32x4 sa[4] = {};
#pragma unroll
    for (int kk = 0; kk < 2; ++kk)
#pragma unroll
      for (int nj = 0; nj < 4; ++nj) {
        const short8 kf = *(const short8*)((const char*)Ks[cur] + (nj * 16 + lr) * 128 +
                                           ((kk * 64 + lk * 16) ^ rswz));
        sa[nj] = __builtin_amdgcn_mfma_f32_16x16x32_bf16(qf[kk], kf, sa[nj], 0, 0, 0);
      }

    if (t == qt) {  // diagonal tile: causal mask (col > row -> -inf)
#pragma unroll
      for (int nj = 0; nj < 4; ++nj)
#pragma unroll
        for (int r = 0; r < 4; ++r)
          if (nj * 16 + lr > w * 16 + lk * 4 + r) sa[nj][r] = -1e30f;
    }

    // online softmax: max reduced across 16 lanes; l kept as PER-LANE partial
#pragma unroll
    for (int r = 0; r < 4; ++r) {
      float mx = fmaxf(fmaxf(sa[0][r], sa[1][r]), fmaxf(sa[2][r], sa[3][r]));
#pragma unroll
      for (int d = 1; d < 16; d <<= 1) mx = fmaxf(mx, __shfl_xor(mx, d));
      const float mn = fmaxf(mrow[r], mx);
      const float sc = __expf(mrow[r] - mn);   // lane-uniform within row
      mrow[r] = mn;
      float rs = 0.f;
#pragma unroll
      for (int nj = 0; nj < 4; ++nj) {
        const float p = __expf(sa[nj][r] - mn);
        sa[nj][r] = p;
        rs += p;
      }
      lrow[r] = lrow[r] * sc + rs;             // per-lane partial (4 cols/lane)
#pragma unroll
      for (int nj = 0; nj < 4; ++nj) o[nj][r] *= sc;
    }

    // P -> LDS (bf16, swizzled; wave-private 16-row slab, no barrier needed)
#pragma unroll
    for (int nj = 0; nj < 4; ++nj)
#pragma unroll
      for (int r = 0; r < 4; ++r) {
        const int rp = w * 16 + lk * 4 + r;
        *(u16*)((char*)Ps + rp * 128 + (((nj * 16 + lr) * 2) ^ ((rp & 7) << 4))) =
            f2bf(sa[nj][r]);
      }

    // O += P @ V
#pragma unroll
    for (int kk = 0; kk < 2; ++kk) {
      const short8 pa = *(const short8*)((const char*)Ps + (w * 16 + lr) * 128 +
                                         ((kk * 64 + lk * 16) ^ rswz));
#pragma unroll
      for (int nj = 0; nj < 4; ++nj) {
        const short8 vf = *(const short8*)((const char*)Vs[cur] + (nj * 16 + lr) * 128 +
                                           ((kk * 64 + lk * 16) ^ rswz));
        o[nj] = __builtin_amdgcn_mfma_f32_16x16x32_bf16(pa, vf, o[nj], 0, 0, 0);
      }
    }
    __syncthreads();   // drains next-tile stage (flew during compute) + barrier
    cur ^= 1;
  }

#pragma unroll
  for (int r = 0; r < 4; ++r) {
    // finalize l: reduce per-lane partials across the row's 16 lanes
    float lt = lrow[r];
#pragma unroll
    for (int d = 1; d < 16; d <<= 1) lt += __shfl_xor(lt, d);
    const int rowq = q0 + w * 16 + lk * 4 + r;
    const float inv = 1.f / lt;
    float rsum = 0.f;
#pragma unroll
    for (int nj = 0; nj < 4; ++nj) {
      const float v = o[nj][r] * inv;
      O[((size_t)(b * S_ + rowq)) * D_ + h * 64 + nj * 16 + lr] = f2bf(v);
      rsum += v;
    }
#pragma unroll
    for (int d = 1; d < 16; d <<= 1) rsum += __shfl_xor(rsum, d);
    if (lr == 0) AW[(size_t)bh * S_ + rowq] = rsum * (1.f / 64.f);
  }
}

extern "C" void kernel_launch(void* const* d_in, const int* in_sizes, int n_in,
                              void* d_out, int out_size, void* d_ws, size_t ws_size,
                              hipStream_t stream) {
  const float* q  = (const float*)d_in[0];
  const float* k  = (const float*)d_in[1];
  const float* v  = (const float*)d_in[2];
  const float* Wq = (const float*)d_in[4];
  const float* bq = (const float*)d_in[5];
  const float* Wk = (const float*)d_in[6];
  const float* bk = (const float*)d_in[7];
  const float* Wv = (const float*)d_in[8];
  const float* bv = (const float*)d_in[9];
  const float* Wo = (const float*)d_in[10];
  const float* bo = (const float*)d_in[11];
  float* out = (float*)d_out;
  float* aw  = out + (size_t)M_ * D_;   // attn_weights tail [B,H,S]

  char* ws = (char*)d_ws;               // 40 MB total (proven ws >= 48 MB)
  u16* Qh  = (u16*)(ws);                //  0- 8 MB
  u16* Kh  = (u16*)(ws + (8u << 20));   //  8-16
  u16* Vtb = (u16*)(ws + (16u << 20));  // 16-24
  u16* Ob  = (u16*)(ws + (24u << 20));  // 24-32
  u16* Wqb = (u16*)(ws + (32u << 20));  // 32-34
  u16* Wkb = (u16*)(ws + (34u << 20));
  u16* Wvb = (u16*)(ws + (36u << 20));
  u16* Wob = (u16*)(ws + (38u << 20));

  cvt4w<<<dim3(1024, 4), 256, 0, stream>>>(Wq, Wk, Wv, Wo, Wqb, Wkb, Wvb, Wob);

  gemm_qkv<<<dim3(8, 32, 3), 256, 0, stream>>>(q, k, v, Wqb, Wkb, Wvb,
                                               bq, bk, bv, Qh, Kh, Vtb);

  flash64<<<dim3(B_ * H_, S_ / 64), 256, 0, stream>>>(Qh, Kh, Vtb, Ob, aw);

  gemm_out<<<dim3(8, 32), 256, 0, stream>>>(Ob, Wob, bo, out);
}

// Round 7
// 278.384 us; speedup vs baseline: 1.3634x; 1.0846x over previous
//
#include <hip/hip_runtime.h>
#include <hip/hip_bf16.h>
#include <stdint.h>

#define B_ 2
#define S_ 2048
#define D_ 1024
#define H_ 16
#define DK_ 64
#define M_ 4096   // B_*S_
#define K_ 1024

typedef unsigned short u16;
typedef u16   u16x4  __attribute__((ext_vector_type(4)));
typedef short short8 __attribute__((ext_vector_type(8)));
typedef float f32x4  __attribute__((ext_vector_type(4)));

__device__ __forceinline__ u16 f2bf(float f) {
  uint32_t u = __builtin_bit_cast(uint32_t, f);
  u += 0x7FFFu + ((u >> 16) & 1u);   // RNE
  return (u16)(u >> 16);
}

__device__ __forceinline__ void gload_lds16(const void* g, void* l) {
  __builtin_amdgcn_global_load_lds(
      (const __attribute__((address_space(1))) void*)g,
      (__attribute__((address_space(3))) void*)l, 16, 0, 0);
}

// ---------------- fp32 -> bf16 weight converts, 4 tensors in one launch ----
__global__ __launch_bounds__(256) void cvt4w(const float* __restrict__ a,
                                             const float* __restrict__ b,
                                             const float* __restrict__ c,
                                             const float* __restrict__ d,
                                             u16* __restrict__ oa, u16* __restrict__ ob,
                                             u16* __restrict__ oc, u16* __restrict__ od) {
  const int z = blockIdx.y;
  const float* in = z == 0 ? a : (z == 1 ? b : (z == 2 ? c : d));
  u16* out = z == 0 ? oa : (z == 1 ? ob : (z == 2 ? oc : od));
  const int i = (blockIdx.x * 256 + threadIdx.x) * 4;
  const float4 v = *(const float4*)(in + i);
  u16x4 o;
  o[0] = f2bf(v.x); o[1] = f2bf(v.y); o[2] = f2bf(v.z); o[3] = f2bf(v.w);
  *(u16x4*)(out + i) = o;
}

// ---------------- fused QKV GEMM: 3 blocks/CU, fp32 A staged raw ----------
// XOR-swizzled LDS (both-sides involution, same scheme as flash64):
//   LDS[row][c] = global[row][c ^ ((row&7)<<4)]  via pre-swizzled source col;
//   every read applies the same XOR.  Kills the 16-way read conflicts
//   (SQ_LDS_BANK_CONFLICT 2.67e7 @ round 6).
// z=0: Q -> [B,H,S,DK] *0.125   z=1: K -> [B,H,S,DK]   z=2: V -> [B,H,DK,S]
__global__ __launch_bounds__(256) void gemm_qkv(
    const float* __restrict__ Aq, const float* __restrict__ Ak, const float* __restrict__ Av,
    const u16* __restrict__ Wqp, const u16* __restrict__ Wkp, const u16* __restrict__ Wvp,
    const float* __restrict__ bqp, const float* __restrict__ bkp, const float* __restrict__ bvp,
    u16* __restrict__ oq, u16* __restrict__ okk, u16* __restrict__ ov) {
  __shared__ float As[128 * 64];   // 32 KB fp32 activations, 256 B rows
  __shared__ u16  Bs[128 * 64];    // 16 KB bf16 weights, 128 B rows
  const int z = blockIdx.z;
  const float* A    = z == 0 ? Aq  : (z == 1 ? Ak  : Av);
  const u16*   W    = z == 0 ? Wqp : (z == 1 ? Wkp : Wvp);
  const float* bias = z == 0 ? bqp : (z == 1 ? bkp : bvp);
  u16* out          = z == 0 ? oq  : (z == 1 ? okk : ov);
  const float scale = z == 0 ? 0.125f : 1.0f;

  const int tid = threadIdx.x;
  const int w = tid >> 6, lane = tid & 63;
  const int lr = lane & 15, lk = lane >> 4;
  const int wr = w >> 1, wc = w & 1;
  const int m0 = blockIdx.y * 128, n0 = blockIdx.x * 128;

  f32x4 acc[4][4] = {};

  const int arow   = w * 4 + (lane >> 4);   // A stage: 4 fp32 rows/wave per iter
  const int acolsz = ((lane & 15) * 16) ^ ((arow & 7) << 4);  // pre-swizzled src col
  const int trow   = tid >> 3;              // W stage: 8 bf16 rows/wave per iter
  const int tcolsz = ((tid & 7) * 16) ^ ((trow & 7) << 4);
  const int rswz   = (lr & 7) << 4;         // read-side XOR (row&7 == lr&7)
  const u16* Wbase = W + (size_t)(n0 + trow) * K_;

  for (int k0 = 0; k0 < K_; k0 += 64) {
#pragma unroll
    for (int i = 0; i < 8; ++i) {
      const char* ga = (const char*)(A + (size_t)(m0 + i * 16 + arow) * K_ + k0) + acolsz;
      gload_lds16(ga, (char*)As + i * 4096 + w * 1024);
    }
#pragma unroll
    for (int i = 0; i < 4; ++i) {
      const char* gb = (const char*)(Wbase + (size_t)(i * 32) * K_ + k0) + tcolsz;
      gload_lds16(gb, (char*)Bs + i * 4096 + w * 1024);
    }
    __syncthreads();
#pragma unroll
    for (int kk = 0; kk < 2; ++kk) {
      short8 af[4], bf[4];
#pragma unroll
      for (int mi = 0; mi < 4; ++mi) {
        const char* ap = (const char*)As + (wr * 64 + mi * 16 + lr) * 256;
        const f32x4 lo = *(const f32x4*)(ap + ((kk * 128 + lk * 32) ^ rswz));
        const f32x4 hi = *(const f32x4*)(ap + ((kk * 128 + lk * 32 + 16) ^ rswz));
#pragma unroll
        for (int e = 0; e < 4; ++e) {
          af[mi][e]     = (short)f2bf(lo[e]);
          af[mi][4 + e] = (short)f2bf(hi[e]);
        }
      }
#pragma unroll
      for (int nj = 0; nj < 4; ++nj)
        bf[nj] = *(const short8*)((const char*)Bs + (wc * 64 + nj * 16 + lr) * 128 +
                                  ((kk * 64 + lk * 16) ^ rswz));
#pragma unroll
      for (int mi = 0; mi < 4; ++mi)
#pragma unroll
        for (int nj = 0; nj < 4; ++nj)
          acc[mi][nj] = __builtin_amdgcn_mfma_f32_16x16x32_bf16(af[mi], bf[nj],
                                                                acc[mi][nj], 0, 0, 0);
    }
    __syncthreads();
  }

#pragma unroll
  for (int nj = 0; nj < 4; ++nj) {
    const int col = n0 + wc * 64 + nj * 16 + lr;
    const float bv = bias[col];
    const int h = col >> 6, dk = col & 63;
#pragma unroll
    for (int mi = 0; mi < 4; ++mi) {
#pragma unroll
      for (int r = 0; r < 4; ++r) {
        const int row = m0 + wr * 64 + mi * 16 + lk * 4 + r;
        const float val = (acc[mi][nj][r] + bv) * scale;
        const int b = row >> 11, s = row & 2047;
        if (z != 2)
          out[((size_t)(b * H_ + h) * S_ + s) * DK_ + dk] = f2bf(val);
        else
          out[((size_t)(b * H_ + h) * DK_ + dk) * S_ + s] = f2bf(val);
      }
    }
  }
}

// ---------------- out-projection GEMM (bf16 A, fp32 out), swizzled ---------
__global__ __launch_bounds__(256) void gemm_out(const u16* __restrict__ A,
                                                const u16* __restrict__ W,
                                                const float* __restrict__ bias,
                                                float* __restrict__ out) {
  __shared__ u16 As[128 * 64];
  __shared__ u16 Bs[128 * 64];
  const int tid = threadIdx.x;
  const int w = tid >> 6, lane = tid & 63;
  const int lr = lane & 15, lk = lane >> 4;
  const int wr = w >> 1, wc = w & 1;
  const int m0 = blockIdx.y * 128, n0 = blockIdx.x * 128;

  f32x4 acc[4][4] = {};

  const int trow   = tid >> 3;
  const int tcolsz = ((tid & 7) * 16) ^ ((trow & 7) << 4);
  const int rswz   = (lr & 7) << 4;
  const u16* Abase = A + (size_t)(m0 + trow) * K_;
  const u16* Wbase = W + (size_t)(n0 + trow) * K_;

  for (int k0 = 0; k0 < K_; k0 += 64) {
#pragma unroll
    for (int i = 0; i < 4; ++i) {
      const char* ga = (const char*)(Abase + (size_t)(i * 32) * K_ + k0) + tcolsz;
      gload_lds16(ga, (char*)As + i * 4096 + w * 1024);
      const char* gb = (const char*)(Wbase + (size_t)(i * 32) * K_ + k0) + tcolsz;
      gload_lds16(gb, (char*)Bs + i * 4096 + w * 1024);
    }
    __syncthreads();
#pragma unroll
    for (int kk = 0; kk < 2; ++kk) {
      short8 af[4], bf[4];
#pragma unroll
      for (int mi = 0; mi < 4; ++mi)
        af[mi] = *(const short8*)((const char*)As + (wr * 64 + mi * 16 + lr) * 128 +
                                  ((kk * 64 + lk * 16) ^ rswz));
#pragma unroll
      for (int nj = 0; nj < 4; ++nj)
        bf[nj] = *(const short8*)((const char*)Bs + (wc * 64 + nj * 16 + lr) * 128 +
                                  ((kk * 64 + lk * 16) ^ rswz));
#pragma unroll
      for (int mi = 0; mi < 4; ++mi)
#pragma unroll
        for (int nj = 0; nj < 4; ++nj)
          acc[mi][nj] = __builtin_amdgcn_mfma_f32_16x16x32_bf16(af[mi], bf[nj],
                                                                acc[mi][nj], 0, 0, 0);
    }
    __syncthreads();
  }

#pragma unroll
  for (int nj = 0; nj < 4; ++nj) {
    const int col = n0 + wc * 64 + nj * 16 + lr;
    const float bv = bias[col];
#pragma unroll
    for (int mi = 0; mi < 4; ++mi)
#pragma unroll
      for (int r = 0; r < 4; ++r) {
        const int row = m0 + wr * 64 + mi * 16 + lk * 4 + r;
        out[(size_t)row * D_ + col] = acc[mi][nj][r] + bv;
      }
  }
}

// ---------------- flash attention v2: double-buffered, XCD-local -----------
// grid = (B*H, S/64).  bh = blockIdx.x  => same-bh blocks land on same XCD.
// qt reversed => longest blocks first.  K/V double-buffered: STAGE(t+1)
// issued BEFORE compute(t); single __syncthreads per iter AFTER compute.
__global__ __launch_bounds__(256) void flash64(const u16* __restrict__ Qh,
                                               const u16* __restrict__ Kh,
                                               const u16* __restrict__ Vt,
                                               u16* __restrict__ O,
                                               float* __restrict__ AW) {
  __shared__ u16 Ks[2][64 * 64];
  __shared__ u16 Vs[2][64 * 64];   // [dk][kv]
  __shared__ u16 Ps[64 * 64];
  const int tid = threadIdx.x;
  const int w = tid >> 6, lane = tid & 63;
  const int lr = lane & 15, lk = lane >> 4;
  const int bh = blockIdx.x;                    // b*H + h
  const int qt = (gridDim.y - 1) - blockIdx.y;  // longest-first
  const int q0 = qt * 64;
  const int b = bh >> 4, h = bh & 15;
  const int nt = qt + 1;

  const u16* Qg = Qh + ((size_t)bh * S_ + q0 + w * 16 + lr) * DK_;
  short8 qf[2];
  qf[0] = *(const short8*)(Qg + lk * 8);
  qf[1] = *(const short8*)(Qg + 32 + lk * 8);

  float mrow[4], lrow[4];
  f32x4 o[4] = {};
#pragma unroll
  for (int r = 0; r < 4; ++r) { mrow[r] = -__builtin_inff(); lrow[r] = 0.f; }

  const int trow = tid >> 3;
  const int tswz = ((tid & 7) * 16) ^ ((trow & 7) << 4);   // pre-swizzled source col
  const int rswz = (lr & 7) << 4;                          // read-side XOR
  const u16* Kgb = Kh + (size_t)bh * S_ * DK_;
  const u16* Vgb = Vt + (size_t)bh * DK_ * S_;

  auto STAGE = [&](int t, int d) {
    const int kv0 = t * 64;
#pragma unroll
    for (int i = 0; i < 2; ++i) {
      const char* gk = (const char*)(Kgb + (size_t)(kv0 + i * 32 + trow) * DK_) + tswz;
      gload_lds16(gk, (char*)Ks[d] + i * 4096 + w * 1024);
      const char* gv = (const char*)(Vgb + (size_t)(i * 32 + trow) * S_ + kv0) + tswz;
      gload_lds16(gv, (char*)Vs[d] + i * 4096 + w * 1024);
    }
  };

  STAGE(0, 0);
  __syncthreads();

  int cur = 0;
  for (int t = 0; t < nt; ++t) {
    if (t + 1 < nt) STAGE(t + 1, cur ^ 1);   // issue next-tile loads early

    // S = Q K^T (Q already has 1/sqrt(dk))
    f32x4 sa[4] = {};
#pragma unroll
    for (int kk = 0; kk < 2; ++kk)
#pragma unroll
      for (int nj = 0; nj < 4; ++nj) {
        const short8 kf = *(const short8*)((const char*)Ks[cur] + (nj * 16 + lr) * 128 +
                                           ((kk * 64 + lk * 16) ^ rswz));
        sa[nj] = __builtin_amdgcn_mfma_f32_16x16x32_bf16(qf[kk], kf, sa[nj], 0, 0, 0);
      }

    if (t == qt) {  // diagonal tile: causal mask (col > row -> -inf)
#pragma unroll
      for (int nj = 0; nj < 4; ++nj)
#pragma unroll
        for (int r = 0; r < 4; ++r)
          if (nj * 16 + lr > w * 16 + lk * 4 + r) sa[nj][r] = -1e30f;
    }

    // online softmax: max reduced across 16 lanes; l kept as PER-LANE partial
#pragma unroll
    for (int r = 0; r < 4; ++r) {
      float mx = fmaxf(fmaxf(sa[0][r], sa[1][r]), fmaxf(sa[2][r], sa[3][r]));
#pragma unroll
      for (int d = 1; d < 16; d <<= 1) mx = fmaxf(mx, __shfl_xor(mx, d));
      const float mn = fmaxf(mrow[r], mx);
      const float sc = __expf(mrow[r] - mn);   // lane-uniform within row
      mrow[r] = mn;
      float rs = 0.f;
#pragma unroll
      for (int nj = 0; nj < 4; ++nj) {
        const float p = __expf(sa[nj][r] - mn);
        sa[nj][r] = p;
        rs += p;
      }
      lrow[r] = lrow[r] * sc + rs;             // per-lane partial (4 cols/lane)
#pragma unroll
      for (int nj = 0; nj < 4; ++nj) o[nj][r] *= sc;
    }

    // P -> LDS (bf16, swizzled; wave-private 16-row slab, no barrier needed)
#pragma unroll
    for (int nj = 0; nj < 4; ++nj)
#pragma unroll
      for (int r = 0; r < 4; ++r) {
        const int rp = w * 16 + lk * 4 + r;
        *(u16*)((char*)Ps + rp * 128 + (((nj * 16 + lr) * 2) ^ ((rp & 7) << 4))) =
            f2bf(sa[nj][r]);
      }

    // O += P @ V
#pragma unroll
    for (int kk = 0; kk < 2; ++kk) {
      const short8 pa = *(const short8*)((const char*)Ps + (w * 16 + lr) * 128 +
                                         ((kk * 64 + lk * 16) ^ rswz));
#pragma unroll
      for (int nj = 0; nj < 4; ++nj) {
        const short8 vf = *(const short8*)((const char*)Vs[cur] + (nj * 16 + lr) * 128 +
                                           ((kk * 64 + lk * 16) ^ rswz));
        o[nj] = __builtin_amdgcn_mfma_f32_16x16x32_bf16(pa, vf, o[nj], 0, 0, 0);
      }
    }
    __syncthreads();   // drains next-tile stage (flew during compute) + barrier
    cur ^= 1;
  }

#pragma unroll
  for (int r = 0; r < 4; ++r) {
    // finalize l: reduce per-lane partials across the row's 16 lanes
    float lt = lrow[r];
#pragma unroll
    for (int d = 1; d < 16; d <<= 1) lt += __shfl_xor(lt, d);
    const int rowq = q0 + w * 16 + lk * 4 + r;
    const float inv = 1.f / lt;
    float rsum = 0.f;
#pragma unroll
    for (int nj = 0; nj < 4; ++nj) {
      const float v = o[nj][r] * inv;
      O[((size_t)(b * S_ + rowq)) * D_ + h * 64 + nj * 16 + lr] = f2bf(v);
      rsum += v;
    }
#pragma unroll
    for (int d = 1; d < 16; d <<= 1) rsum += __shfl_xor(rsum, d);
    if (lr == 0) AW[(size_t)bh * S_ + rowq] = rsum * (1.f / 64.f);
  }
}

extern "C" void kernel_launch(void* const* d_in, const int* in_sizes, int n_in,
                              void* d_out, int out_size, void* d_ws, size_t ws_size,
                              hipStream_t stream) {
  const float* q  = (const float*)d_in[0];
  const float* k  = (const float*)d_in[1];
  const float* v  = (const float*)d_in[2];
  const float* Wq = (const float*)d_in[4];
  const float* bq = (const float*)d_in[5];
  const float* Wk = (const float*)d_in[6];
  const float* bk = (const float*)d_in[7];
  const float* Wv = (const float*)d_in[8];
  const float* bv = (const float*)d_in[9];
  const float* Wo = (const float*)d_in[10];
  const float* bo = (const float*)d_in[11];
  float* out = (float*)d_out;
  float* aw  = out + (size_t)M_ * D_;   // attn_weights tail [B,H,S]

  char* ws = (char*)d_ws;               // 40 MB total (proven ws >= 48 MB)
  u16* Qh  = (u16*)(ws);                //  0- 8 MB
  u16* Kh  = (u16*)(ws + (8u << 20));   //  8-16
  u16* Vtb = (u16*)(ws + (16u << 20));  // 16-24
  u16* Ob  = (u16*)(ws + (24u << 20));  // 24-32
  u16* Wqb = (u16*)(ws + (32u << 20));  // 32-34
  u16* Wkb = (u16*)(ws + (34u << 20));
  u16* Wvb = (u16*)(ws + (36u << 20));
  u16* Wob = (u16*)(ws + (38u << 20));

  cvt4w<<<dim3(1024, 4), 256, 0, stream>>>(Wq, Wk, Wv, Wo, Wqb, Wkb, Wvb, Wob);

  gemm_qkv<<<dim3(8, 32, 3), 256, 0, stream>>>(q, k, v, Wqb, Wkb, Wvb,
                                               bq, bk, bv, Qh, Kh, Vtb);

  flash64<<<dim3(B_ * H_, S_ / 64), 256, 0, stream>>>(Qh, Kh, Vtb, Ob, aw);

  gemm_out<<<dim3(8, 32), 256, 0, stream>>>(Ob, Wob, bo, out);
}

// Round 8
// 267.591 us; speedup vs baseline: 1.4184x; 1.0403x over previous
//
#include <hip/hip_runtime.h>
#include <hip/hip_bf16.h>
#include <stdint.h>

#define B_ 2
#define S_ 2048
#define D_ 1024
#define H_ 16
#define DK_ 64
#define M_ 4096   // B_*S_
#define K_ 1024

typedef unsigned short u16;
typedef u16   u16x4  __attribute__((ext_vector_type(4)));
typedef short short8 __attribute__((ext_vector_type(8)));
typedef float f32x4  __attribute__((ext_vector_type(4)));
typedef uint32_t u32x4 __attribute__((ext_vector_type(4)));

__device__ __forceinline__ u16 f2bf(float f) {
  uint32_t u = __builtin_bit_cast(uint32_t, f);
  u += 0x7FFFu + ((u >> 16) & 1u);   // RNE
  return (u16)(u >> 16);
}

__device__ __forceinline__ uint32_t cvtpk(float lo, float hi) {
  uint32_t r;
  asm("v_cvt_pk_bf16_f32 %0, %1, %2" : "=v"(r) : "v"(lo), "v"(hi));
  return r;
}

__device__ __forceinline__ void gload_lds16(const void* g, void* l) {
  __builtin_amdgcn_global_load_lds(
      (const __attribute__((address_space(1))) void*)g,
      (__attribute__((address_space(3))) void*)l, 16, 0, 0);
}

// ---------------- fp32 -> bf16 weight converts, 4 tensors in one launch ----
__global__ __launch_bounds__(256) void cvt4w(const float* __restrict__ a,
                                             const float* __restrict__ b,
                                             const float* __restrict__ c,
                                             const float* __restrict__ d,
                                             u16* __restrict__ oa, u16* __restrict__ ob,
                                             u16* __restrict__ oc, u16* __restrict__ od) {
  const int z = blockIdx.y;
  const float* in = z == 0 ? a : (z == 1 ? b : (z == 2 ? c : d));
  u16* out = z == 0 ? oa : (z == 1 ? ob : (z == 2 ? oc : od));
  const int i = (blockIdx.x * 256 + threadIdx.x) * 4;
  const float4 v = *(const float4*)(in + i);
  u16x4 o;
  o[0] = f2bf(v.x); o[1] = f2bf(v.y); o[2] = f2bf(v.z); o[3] = f2bf(v.w);
  *(u16x4*)(out + i) = o;
}

// ---------------- fused QKV GEMM: XCD-chunked, cvt_pk fragments ------------
// 1-D grid 768; tile T = (g&7)*96 + (g>>3)  [m204 bijective XCD swizzle]:
// each XCD owns 12 contiguous m-rows x all 8 n-tiles x (partial) z => the
// 512 KB A-panel is fetched ONCE per XCD's L2 instead of 8x across XCDs.
// LDS XOR-swizzled (round-7, conflicts 2.67e7 -> 3.1e6).  A-fragments
// converted fp32->bf16 via v_cvt_pk_bf16_f32 (1 VALU op / 2 elems) instead
// of 4-op scalar bit-math (round-7 VALUBusy 22% tax).
// z=0: Q -> [B,H,S,DK] *0.125   z=1: K -> [B,H,S,DK]   z=2: V -> [B,H,DK,S]
__global__ __launch_bounds__(256) void gemm_qkv(
    const float* __restrict__ Aq, const float* __restrict__ Ak, const float* __restrict__ Av,
    const u16* __restrict__ Wqp, const u16* __restrict__ Wkp, const u16* __restrict__ Wvp,
    const float* __restrict__ bqp, const float* __restrict__ bkp, const float* __restrict__ bvp,
    u16* __restrict__ oq, u16* __restrict__ okk, u16* __restrict__ ov) {
  __shared__ float As[128 * 64];   // 32 KB fp32 activations, 256 B rows
  __shared__ u16  Bs[128 * 64];    // 16 KB bf16 weights, 128 B rows

  const int g = blockIdx.x;
  const int T = (g & 7) * 96 + (g >> 3);   // XCD-chunked tile id
  const int z = T >> 8;
  const int rem = T & 255;
  const int m0 = (rem >> 3) * 128, n0 = (rem & 7) * 128;

  const float* A    = z == 0 ? Aq  : (z == 1 ? Ak  : Av);
  const u16*   W    = z == 0 ? Wqp : (z == 1 ? Wkp : Wvp);
  const float* bias = z == 0 ? bqp : (z == 1 ? bkp : bvp);
  u16* out          = z == 0 ? oq  : (z == 1 ? okk : ov);
  const float scale = z == 0 ? 0.125f : 1.0f;

  const int tid = threadIdx.x;
  const int w = tid >> 6, lane = tid & 63;
  const int lr = lane & 15, lk = lane >> 4;
  const int wr = w >> 1, wc = w & 1;

  f32x4 acc[4][4] = {};

  const int arow   = w * 4 + (lane >> 4);   // A stage: 4 fp32 rows/wave per iter
  const int acolsz = ((lane & 15) * 16) ^ ((arow & 7) << 4);  // pre-swizzled src col
  const int trow   = tid >> 3;              // W stage: 8 bf16 rows/wave per iter
  const int tcolsz = ((tid & 7) * 16) ^ ((trow & 7) << 4);
  const int rswz   = (lr & 7) << 4;         // read-side XOR (row&7 == lr&7)
  const u16* Wbase = W + (size_t)(n0 + trow) * K_;

  for (int k0 = 0; k0 < K_; k0 += 64) {
#pragma unroll
    for (int i = 0; i < 8; ++i) {
      const char* ga = (const char*)(A + (size_t)(m0 + i * 16 + arow) * K_ + k0) + acolsz;
      gload_lds16(ga, (char*)As + i * 4096 + w * 1024);
    }
#pragma unroll
    for (int i = 0; i < 4; ++i) {
      const char* gb = (const char*)(Wbase + (size_t)(i * 32) * K_ + k0) + tcolsz;
      gload_lds16(gb, (char*)Bs + i * 4096 + w * 1024);
    }
    __syncthreads();
#pragma unroll
    for (int kk = 0; kk < 2; ++kk) {
      short8 af[4], bf[4];
#pragma unroll
      for (int mi = 0; mi < 4; ++mi) {
        const char* ap = (const char*)As + (wr * 64 + mi * 16 + lr) * 256;
        const f32x4 lo = *(const f32x4*)(ap + ((kk * 128 + lk * 32) ^ rswz));
        const f32x4 hi = *(const f32x4*)(ap + ((kk * 128 + lk * 32 + 16) ^ rswz));
        u32x4 pk;
        pk[0] = cvtpk(lo[0], lo[1]);
        pk[1] = cvtpk(lo[2], lo[3]);
        pk[2] = cvtpk(hi[0], hi[1]);
        pk[3] = cvtpk(hi[2], hi[3]);
        af[mi] = __builtin_bit_cast(short8, pk);
      }
#pragma unroll
      for (int nj = 0; nj < 4; ++nj)
        bf[nj] = *(const short8*)((const char*)Bs + (wc * 64 + nj * 16 + lr) * 128 +
                                  ((kk * 64 + lk * 16) ^ rswz));
#pragma unroll
      for (int mi = 0; mi < 4; ++mi)
#pragma unroll
        for (int nj = 0; nj < 4; ++nj)
          acc[mi][nj] = __builtin_amdgcn_mfma_f32_16x16x32_bf16(af[mi], bf[nj],
                                                                acc[mi][nj], 0, 0, 0);
    }
    __syncthreads();
  }

#pragma unroll
  for (int nj = 0; nj < 4; ++nj) {
    const int col = n0 + wc * 64 + nj * 16 + lr;
    const float bv = bias[col];
    const int h = col >> 6, dk = col & 63;
#pragma unroll
    for (int mi = 0; mi < 4; ++mi) {
#pragma unroll
      for (int r = 0; r < 4; ++r) {
        const int row = m0 + wr * 64 + mi * 16 + lk * 4 + r;
        const float val = (acc[mi][nj][r] + bv) * scale;
        const int b = row >> 11, s = row & 2047;
        if (z != 2)
          out[((size_t)(b * H_ + h) * S_ + s) * DK_ + dk] = f2bf(val);
        else
          out[((size_t)(b * H_ + h) * DK_ + dk) * S_ + s] = f2bf(val);
      }
    }
  }
}

// ---------------- out-projection GEMM (bf16 A, fp32 out), swizzled+chunked -
__global__ __launch_bounds__(256) void gemm_out(const u16* __restrict__ A,
                                                const u16* __restrict__ W,
                                                const float* __restrict__ bias,
                                                float* __restrict__ out) {
  __shared__ u16 As[128 * 64];
  __shared__ u16 Bs[128 * 64];
  const int g = blockIdx.x;
  const int T = (g & 7) * 32 + (g >> 3);   // XCD-chunked tile id (256 tiles)
  const int m0 = (T >> 3) * 128, n0 = (T & 7) * 128;

  const int tid = threadIdx.x;
  const int w = tid >> 6, lane = tid & 63;
  const int lr = lane & 15, lk = lane >> 4;
  const int wr = w >> 1, wc = w & 1;

  f32x4 acc[4][4] = {};

  const int trow   = tid >> 3;
  const int tcolsz = ((tid & 7) * 16) ^ ((trow & 7) << 4);
  const int rswz   = (lr & 7) << 4;
  const u16* Abase = A + (size_t)(m0 + trow) * K_;
  const u16* Wbase = W + (size_t)(n0 + trow) * K_;

  for (int k0 = 0; k0 < K_; k0 += 64) {
#pragma unroll
    for (int i = 0; i < 4; ++i) {
      const char* ga = (const char*)(Abase + (size_t)(i * 32) * K_ + k0) + tcolsz;
      gload_lds16(ga, (char*)As + i * 4096 + w * 1024);
      const char* gb = (const char*)(Wbase + (size_t)(i * 32) * K_ + k0) + tcolsz;
      gload_lds16(gb, (char*)Bs + i * 4096 + w * 1024);
    }
    __syncthreads();
#pragma unroll
    for (int kk = 0; kk < 2; ++kk) {
      short8 af[4], bf[4];
#pragma unroll
      for (int mi = 0; mi < 4; ++mi)
        af[mi] = *(const short8*)((const char*)As + (wr * 64 + mi * 16 + lr) * 128 +
                                  ((kk * 64 + lk * 16) ^ rswz));
#pragma unroll
      for (int nj = 0; nj < 4; ++nj)
        bf[nj] = *(const short8*)((const char*)Bs + (wc * 64 + nj * 16 + lr) * 128 +
                                  ((kk * 64 + lk * 16) ^ rswz));
#pragma unroll
      for (int mi = 0; mi < 4; ++mi)
#pragma unroll
        for (int nj = 0; nj < 4; ++nj)
          acc[mi][nj] = __builtin_amdgcn_mfma_f32_16x16x32_bf16(af[mi], bf[nj],
                                                                acc[mi][nj], 0, 0, 0);
    }
    __syncthreads();
  }

#pragma unroll
  for (int nj = 0; nj < 4; ++nj) {
    const int col = n0 + wc * 64 + nj * 16 + lr;
    const float bv = bias[col];
#pragma unroll
    for (int mi = 0; mi < 4; ++mi)
#pragma unroll
      for (int r = 0; r < 4; ++r) {
        const int row = m0 + wr * 64 + mi * 16 + lk * 4 + r;
        out[(size_t)row * D_ + col] = acc[mi][nj][r] + bv;
      }
  }
}

// ---------------- flash attention v2: double-buffered, XCD-local -----------
__global__ __launch_bounds__(256) void flash64(const u16* __restrict__ Qh,
                                               const u16* __restrict__ Kh,
                                               const u16* __restrict__ Vt,
                                               u16* __restrict__ O,
                                               float* __restrict__ AW) {
  __shared__ u16 Ks[2][64 * 64];
  __shared__ u16 Vs[2][64 * 64];   // [dk][kv]
  __shared__ u16 Ps[64 * 64];
  const int tid = threadIdx.x;
  const int w = tid >> 6, lane = tid & 63;
  const int lr = lane & 15, lk = lane >> 4;
  const int bh = blockIdx.x;                    // b*H + h
  const int qt = (gridDim.y - 1) - blockIdx.y;  // longest-first
  const int q0 = qt * 64;
  const int b = bh >> 4, h = bh & 15;
  const int nt = qt + 1;

  const u16* Qg = Qh + ((size_t)bh * S_ + q0 + w * 16 + lr) * DK_;
  short8 qf[2];
  qf[0] = *(const short8*)(Qg + lk * 8);
  qf[1] = *(const short8*)(Qg + 32 + lk * 8);

  float mrow[4], lrow[4];
  f32x4 o[4] = {};
#pragma unroll
  for (int r = 0; r < 4; ++r) { mrow[r] = -__builtin_inff(); lrow[r] = 0.f; }

  const int trow = tid >> 3;
  const int tswz = ((tid & 7) * 16) ^ ((trow & 7) << 4);   // pre-swizzled source col
  const int rswz = (lr & 7) << 4;                          // read-side XOR
  const u16* Kgb = Kh + (size_t)bh * S_ * DK_;
  const u16* Vgb = Vt + (size_t)bh * DK_ * S_;

  auto STAGE = [&](int t, int d) {
    const int kv0 = t * 64;
#pragma unroll
    for (int i = 0; i < 2; ++i) {
      const char* gk = (const char*)(Kgb + (size_t)(kv0 + i * 32 + trow) * DK_) + tswz;
      gload_lds16(gk, (char*)Ks[d] + i * 4096 + w * 1024);
      const char* gv = (const char*)(Vgb + (size_t)(i * 32 + trow) * S_ + kv0) + tswz;
      gload_lds16(gv, (char*)Vs[d] + i * 4096 + w * 1024);
    }
  };

  STAGE(0, 0);
  __syncthreads();

  int cur = 0;
  for (int t = 0; t < nt; ++t) {
    if (t + 1 < nt) STAGE(t + 1, cur ^ 1);   // issue next-tile loads early

    // S = Q K^T (Q already has 1/sqrt(dk))
    f32x4 sa[4] = {};
#pragma unroll
    for (int kk = 0; kk < 2; ++kk)
#pragma unroll
      for (int nj = 0; nj < 4; ++nj) {
        const short8 kf = *(const short8*)((const char*)Ks[cur] + (nj * 16 + lr) * 128 +
                                           ((kk * 64 + lk * 16) ^ rswz));
        sa[nj] = __builtin_amdgcn_mfma_f32_16x16x32_bf16(qf[kk], kf, sa[nj], 0, 0, 0);
      }

    if (t == qt) {  // diagonal tile: causal mask (col > row -> -inf)
#pragma unroll
      for (int nj = 0; nj < 4; ++nj)
#pragma unroll
        for (int r = 0; r < 4; ++r)
          if (nj * 16 + lr > w * 16 + lk * 4 + r) sa[nj][r] = -1e30f;
    }

    // online softmax: max reduced across 16 lanes; l kept as PER-LANE partial
#pragma unroll
    for (int r = 0; r < 4; ++r) {
      float mx = fmaxf(fmaxf(sa[0][r], sa[1][r]), fmaxf(sa[2][r], sa[3][r]));
#pragma unroll
      for (int d = 1; d < 16; d <<= 1) mx = fmaxf(mx, __shfl_xor(mx, d));
      const float mn = fmaxf(mrow[r], mx);
      const float sc = __expf(mrow[r] - mn);   // lane-uniform within row
      mrow[r] = mn;
      float rs = 0.f;
#pragma unroll
      for (int nj = 0; nj < 4; ++nj) {
        const float p = __expf(sa[nj][r] - mn);
        sa[nj][r] = p;
        rs += p;
      }
      lrow[r] = lrow[r] * sc + rs;             // per-lane partial (4 cols/lane)
#pragma unroll
      for (int nj = 0; nj < 4; ++nj) o[nj][r] *= sc;
    }

    // P -> LDS (bf16, swizzled; wave-private 16-row slab, no barrier needed)
#pragma unroll
    for (int nj = 0; nj < 4; ++nj)
#pragma unroll
      for (int r = 0; r < 4; ++r) {
        const int rp = w * 16 + lk * 4 + r;
        *(u16*)((char*)Ps + rp * 128 + (((nj * 16 + lr) * 2) ^ ((rp & 7) << 4))) =
            f2bf(sa[nj][r]);
      }

    // O += P @ V
#pragma unroll
    for (int kk = 0; kk < 2; ++kk) {
      const short8 pa = *(const short8*)((const char*)Ps + (w * 16 + lr) * 128 +
                                         ((kk * 64 + lk * 16) ^ rswz));
#pragma unroll
      for (int nj = 0; nj < 4; ++nj) {
        const short8 vf = *(const short8*)((const char*)Vs[cur] + (nj * 16 + lr) * 128 +
                                           ((kk * 64 + lk * 16) ^ rswz));
        o[nj] = __builtin_amdgcn_mfma_f32_16x16x32_bf16(pa, vf, o[nj], 0, 0, 0);
      }
    }
    __syncthreads();   // drains next-tile stage (flew during compute) + barrier
    cur ^= 1;
  }

#pragma unroll
  for (int r = 0; r < 4; ++r) {
    // finalize l: reduce per-lane partials across the row's 16 lanes
    float lt = lrow[r];
#pragma unroll
    for (int d = 1; d < 16; d <<= 1) lt += __shfl_xor(lt, d);
    const int rowq = q0 + w * 16 + lk * 4 + r;
    const float inv = 1.f / lt;
    float rsum = 0.f;
#pragma unroll
    for (int nj = 0; nj < 4; ++nj) {
      const float v = o[nj][r] * inv;
      O[((size_t)(b * S_ + rowq)) * D_ + h * 64 + nj * 16 + lr] = f2bf(v);
      rsum += v;
    }
#pragma unroll
    for (int d = 1; d < 16; d <<= 1) rsum += __shfl_xor(rsum, d);
    if (lr == 0) AW[(size_t)bh * S_ + rowq] = rsum * (1.f / 64.f);
  }
}

extern "C" void kernel_launch(void* const* d_in, const int* in_sizes, int n_in,
                              void* d_out, int out_size, void* d_ws, size_t ws_size,
                              hipStream_t stream) {
  const float* q  = (const float*)d_in[0];
  const float* k  = (const float*)d_in[1];
  const float* v  = (const float*)d_in[2];
  const float* Wq = (const float*)d_in[4];
  const float* bq = (const float*)d_in[5];
  const float* Wk = (const float*)d_in[6];
  const float* bk = (const float*)d_in[7];
  const float* Wv = (const float*)d_in[8];
  const float* bv = (const float*)d_in[9];
  const float* Wo = (const float*)d_in[10];
  const float* bo = (const float*)d_in[11];
  float* out = (float*)d_out;
  float* aw  = out + (size_t)M_ * D_;   // attn_weights tail [B,H,S]

  char* ws = (char*)d_ws;               // 40 MB total (proven ws >= 48 MB)
  u16* Qh  = (u16*)(ws);                //  0- 8 MB
  u16* Kh  = (u16*)(ws + (8u << 20));   //  8-16
  u16* Vtb = (u16*)(ws + (16u << 20));  // 16-24
  u16* Ob  = (u16*)(ws + (24u << 20));  // 24-32
  u16* Wqb = (u16*)(ws + (32u << 20));  // 32-34
  u16* Wkb = (u16*)(ws + (34u << 20));
  u16* Wvb = (u16*)(ws + (36u << 20));
  u16* Wob = (u16*)(ws + (38u << 20));

  cvt4w<<<dim3(1024, 4), 256, 0, stream>>>(Wq, Wk, Wv, Wo, Wqb, Wkb, Wvb, Wob);

  gemm_qkv<<<768, 256, 0, stream>>>(q, k, v, Wqb, Wkb, Wvb,
                                    bq, bk, bv, Qh, Kh, Vtb);

  flash64<<<dim3(B_ * H_, S_ / 64), 256, 0, stream>>>(Qh, Kh, Vtb, Ob, aw);

  gemm_out<<<256, 256, 0, stream>>>(Ob, Wob, bo, out);
}